// Round 3
// baseline (2819.462 us; speedup 1.0000x reference)
//
#include <hip/hip_runtime.h>
#include <hip/hip_bf16.h>
#include <stdint.h>

#define Bv 2
#define Cv 256
#define Nv 4096
#define NHv 4
#define HDv 64
#define Kv 16

// R2 established: inputs are fp32 (flag=1 path produced finite output where the
// flag=0/bf16 decode NaN'd). Probe retained as cheap insurance; output store
// dtype now follows the same flag.

__device__ __forceinline__ float bf2f(unsigned short u) {
  union { unsigned int i; float f; } x; x.i = ((unsigned int)u) << 16; return x.f;
}
__device__ __forceinline__ unsigned short f2bf(float f) {
  union { float f; unsigned int i; } x; x.f = f;
  unsigned int r = x.i + 0x7FFF + ((x.i >> 16) & 1);   // RNE
  return (unsigned short)(r >> 16);
}
__device__ __forceinline__ float loadf(const void* p, long long i, bool f32) {
  return f32 ? ((const float*)p)[i] : bf2f(((const unsigned short*)p)[i]);
}

__global__ __launch_bounds__(256) void detect_k(const unsigned short* __restrict__ q,
                                                int nwords, int* __restrict__ flag)
{
  __shared__ int hit;
  if (threadIdx.x == 0) hit = 0;
  __syncthreads();
  int local = 0;
  for (int i = threadIdx.x; i < nwords; i += 256) {
    const unsigned int e = (q[i] >> 7) & 0xFF;
    if (e >= 0xC0) local = 1;
  }
  if (local) hit = 1;
  __syncthreads();
  if (threadIdx.x == 0) *flag = hit;
}

// ---------------------------------------------------------------------------
// Tiled GEMM: C[M,Nn] = act(A[M,Kd] @ Bw[Kd,Nn] + bias) (+ Res)
// ADUAL: A is a harness input (dtype per flag); else fp32 workspace.
// A_COL: A element (m,k) at A[k*M + m] (fuses BCHW->BNC transpose).
// ---------------------------------------------------------------------------
template<bool ADUAL, bool A_COL, int ACT, bool RES>
__global__ __launch_bounds__(256) void gemm_k(
    const void* __restrict__ A, const void* __restrict__ Bw,
    const void* __restrict__ bias, const float* __restrict__ Res,
    float* __restrict__ Cc, int M, int Nn, int Kd,
    long long aBatch, long long cBatch, const int* __restrict__ flagp)
{
  const bool f32 = (*flagp != 0);
  __shared__ __align__(16) float As[16][68];
  __shared__ __align__(16) float Bs[16][68];
  const int tid = threadIdx.x;
  const int tx = tid & 15, ty = tid >> 4;
  const int m0 = blockIdx.x * 64, n0 = blockIdx.y * 64;
  const long long ab = (long long)blockIdx.z * aBatch;
  const long long cb = (long long)blockIdx.z * cBatch;

  float acc[4][4];
#pragma unroll
  for (int i = 0; i < 4; ++i)
#pragma unroll
    for (int j = 0; j < 4; ++j) acc[i][j] = 0.f;

  for (int k0 = 0; k0 < Kd; k0 += 16) {
    if (A_COL) {
#pragma unroll
      for (int l = 0; l < 4; ++l) {
        const int idx = tid + l * 256;
        const int m = idx & 63, kk = idx >> 6;
        const long long ai = ab + (long long)(k0 + kk) * M + (m0 + m);
        As[kk][m] = ADUAL ? loadf(A, ai, f32) : ((const float*)A)[ai];
      }
    } else {
#pragma unroll
      for (int l = 0; l < 4; ++l) {
        const int idx = tid + l * 256;
        const int kk = idx & 15, m = idx >> 4;
        const long long ai = ab + (long long)(m0 + m) * Kd + (k0 + kk);
        As[kk][m] = ADUAL ? loadf(A, ai, f32) : ((const float*)A)[ai];
      }
    }
#pragma unroll
    for (int l = 0; l < 4; ++l) {
      const int idx = tid + l * 256;
      const int n = idx & 63, kk = idx >> 6;
      Bs[kk][n] = loadf(Bw, (long long)(k0 + kk) * Nn + (n0 + n), f32);
    }
    __syncthreads();
#pragma unroll
    for (int kk = 0; kk < 16; ++kk) {
      float av[4], bv[4];
      *(float4*)av = *(const float4*)&As[kk][ty * 4];
      *(float4*)bv = *(const float4*)&Bs[kk][tx * 4];
#pragma unroll
      for (int i = 0; i < 4; ++i)
#pragma unroll
        for (int j = 0; j < 4; ++j) acc[i][j] += av[i] * bv[j];
    }
    __syncthreads();
  }
#pragma unroll
  for (int i = 0; i < 4; ++i) {
    const int row = m0 + ty * 4 + i;
#pragma unroll
    for (int j = 0; j < 4; ++j) {
      const int col = n0 + tx * 4 + j;
      float cv = acc[i][j] + loadf(bias, col, f32);
      if (ACT == 1) cv = cv > 0.f ? cv : 0.01f * cv;
      if (RES) cv += Res[cb + (long long)row * Nn + col];
      Cc[cb + (long long)row * Nn + col] = cv;
    }
  }
}

// ---------------------------------------------------------------------------
// Cluster centers
// ---------------------------------------------------------------------------
__global__ __launch_bounds__(256) void zero_k(float* p, int n)
{
  const int i = blockIdx.x * 256 + threadIdx.x;
  if (i < n) p[i] = 0.f;
}

__global__ __launch_bounds__(256) void center_accum(
    const float* __restrict__ kp, const int* __restrict__ labels,
    float* __restrict__ cent, float* __restrict__ cnts)
{
  const int bx = blockIdx.x;           // Bv*Kv*8 blocks
  const int chunk = bx & 7;
  const int kk = (bx >> 3) & 15;
  const int b = bx >> 7;
  const int c = threadIdx.x;
  const int nbase = chunk * (Nv / 8);
  float acc = 0.f;
  int cnt = 0;
  for (int i = 0; i < Nv / 8; ++i) {
    const int n = nbase + i;
    if (labels[b * Nv + n] == kk) {    // wave-uniform branch
      acc += kp[(long long)(b * Nv + n) * Cv + c];
      ++cnt;
    }
  }
  atomicAdd(&cent[(b * Kv + kk) * Cv + c], acc);
  if (c == 0) atomicAdd(&cnts[b * Kv + kk], (float)cnt);
}

__global__ __launch_bounds__(256) void center_norm(float* cent, const float* cnts)
{
  const int i = blockIdx.x * 256 + threadIdx.x;  // Bv*Kv*Cv
  cent[i] = cent[i] / (cnts[i >> 8] + 1e-6f);
}

// ---------------------------------------------------------------------------
// Flash-style adaptive attention.
// ---------------------------------------------------------------------------
__global__ __launch_bounds__(256) void attn_k(
    const float* __restrict__ qp, const float* __restrict__ kp,
    const float* __restrict__ vp, const float* __restrict__ cent,
    const int* __restrict__ labels, const void* __restrict__ pc,
    float* __restrict__ outp, const int* __restrict__ flagp)
{
  const bool f32 = (*flagp != 0);
  __shared__ float q_s[64][65];
  __shared__ float kps[64][65];   // k tile during QK, then p[w*16+r][j]
  __shared__ float v_s[64][65];
  __shared__ float c_s[16][65];
  __shared__ float ac_s[64][16];
  __shared__ int labq_s[64];
  __shared__ int labm_s[64];

  const int tid = threadIdx.x;
  const int lane = tid & 63;
  const int w = tid >> 6;
  const int bx = blockIdx.x;
  const int qt = bx & 63;
  const int h = (bx >> 6) & 3;
  const int b = bx >> 8;
  const int n0 = qt * 64;

  {
    const int d = lane;
#pragma unroll
    for (int i = 0; i < 16; ++i) {
      const int r = w * 16 + i;
      q_s[r][d] = qp[(long long)(b * Nv + n0 + r) * Cv + h * HDv + d] * 0.125f;
    }
    if (tid < 64) labq_s[tid] = labels[b * Nv + n0 + tid];
    for (int idx = tid; idx < Kv * HDv; idx += 256) {
      const int kk = idx >> 6, d2 = idx & 63;
      c_s[kk][d2] = cent[(long long)(b * Kv + kk) * Cv + h * HDv + d2];
    }
  }
  __syncthreads();
  // ac_s[r][k] = (q_r/8) . center_k
  for (int idx = tid; idx < 64 * Kv; idx += 256) {
    const int r = idx >> 4, kk = idx & 15;
    float s = 0.f;
#pragma unroll
    for (int d = 0; d < HDv; ++d) s += q_s[r][d] * c_s[kk][d];
    ac_s[r][kk] = s;
  }

  float mrow[16], lrow[16], acc[16], alpha[16];
#pragma unroll
  for (int r = 0; r < 16; ++r) { mrow[r] = -1e30f; lrow[r] = 0.f; acc[r] = 0.f; }

  const long long pcb = (long long)b * Nv * Nv;
  const int j = lane;

  for (int m0 = 0; m0 < Nv; m0 += 64) {
    __syncthreads();            // previous tile (p, v) fully consumed
    {
      const int d = lane;
#pragma unroll
      for (int i = 0; i < 16; ++i) {
        const int r = w * 16 + i;
        const long long src = (long long)(b * Nv + m0 + r) * Cv + h * HDv + d;
        kps[r][d] = kp[src];
        v_s[r][d] = vp[src];
      }
      if (tid < 64) labm_s[tid] = labels[b * Nv + m0 + tid];
    }
    __syncthreads();

    const int labm = labm_s[j];
    // dense dots: sv[r] = (q_row/8) . k_j  for the wave's 16 rows
    float sv[16];
#pragma unroll
    for (int r = 0; r < 16; ++r) sv[r] = 0.f;
    for (int d0 = 0; d0 < 64; d0 += 16) {
      float kr[16];
#pragma unroll
      for (int t = 0; t < 16; ++t) kr[t] = kps[j][d0 + t];
#pragma unroll
      for (int r = 0; r < 16; ++r) {
        const int row = w * 16 + r;
        float a2 = sv[r];
#pragma unroll
        for (int t = 0; t < 16; ++t) a2 += q_s[row][d0 + t] * kr[t];
        sv[r] = a2;
      }
    }
    __syncthreads();            // all waves done reading k tile -> reuse as p

#pragma unroll
    for (int r = 0; r < 16; ++r) {
      const int row = w * 16 + r;
      const int Ln = labq_s[row];
      float s;
      if (labm == Ln) s = sv[r];
      else s = ac_s[row][labm] *
               loadf(pc, pcb + (long long)(n0 + row) * Nv + m0 + j, f32);
      float mx = s;
#pragma unroll
      for (int off = 32; off > 0; off >>= 1) mx = fmaxf(mx, __shfl_xor(mx, off));
      const float mn = fmaxf(mrow[r], mx);
      const float a = __expf(mrow[r] - mn);
      const float p = __expf(s - mn);
      float ps = p;
#pragma unroll
      for (int off = 32; off > 0; off >>= 1) ps += __shfl_xor(ps, off);
      lrow[r] = lrow[r] * a + ps;
      mrow[r] = mn;
      alpha[r] = a;
      kps[row][j] = p;
    }
    __syncthreads();

    // PV: lane <-> d
    const int dl = lane;
#pragma unroll
    for (int r = 0; r < 16; ++r) acc[r] *= alpha[r];
    for (int j0 = 0; j0 < 64; j0 += 16) {
      float vr[16];
#pragma unroll
      for (int t = 0; t < 16; ++t) vr[t] = v_s[j0 + t][dl];
#pragma unroll
      for (int r = 0; r < 16; ++r) {
        float a2 = acc[r];
#pragma unroll
        for (int t = 0; t < 16; ++t) a2 += kps[w * 16 + r][j0 + t] * vr[t];
        acc[r] = a2;
      }
    }
  }

  {
    const int dl = lane;
#pragma unroll
    for (int r = 0; r < 16; ++r) {
      const int row = w * 16 + r;
      outp[(long long)(b * Nv + n0 + row) * Cv + h * HDv + dl] = acc[r] / lrow[r];
    }
  }
}

// ---------------------------------------------------------------------------
// [B,N,C] fp32 -> [B,C,N] output transpose; store dtype follows flag.
// ---------------------------------------------------------------------------
__global__ __launch_bounds__(256) void transpose_k(const float* __restrict__ in,
                                                   void* __restrict__ out,
                                                   const int* __restrict__ flagp)
{
  const bool f32 = (*flagp != 0);
  __shared__ float t[32][33];
  const int x = threadIdx.x;   // 32
  const int y = threadIdx.y;   // 8
  const int n0 = blockIdx.x * 32, c0 = blockIdx.y * 32, b = blockIdx.z;
  for (int i = y; i < 32; i += 8)
    t[i][x] = in[(long long)(b * Nv + n0 + i) * Cv + c0 + x];
  __syncthreads();
  for (int i = y; i < 32; i += 8) {
    const long long oi = (long long)(b * Cv + c0 + i) * Nv + n0 + x;
    const float v = t[x][i];
    if (f32) ((float*)out)[oi] = v;
    else     ((unsigned short*)out)[oi] = f2bf(v);
  }
}

// ---------------------------------------------------------------------------
extern "C" void kernel_launch(void* const* d_in, const int* in_sizes, int n_in,
                              void* d_out, int out_size, void* d_ws, size_t ws_size,
                              hipStream_t stream)
{
  const void* q_img = d_in[0];
  const void* k_img = d_in[1];
  const void* v_img = d_in[2];
  const int* labels = (const int*)d_in[3];
  const void* pc    = d_in[4];
  const void* Wq  = d_in[5];  const void* bq  = d_in[6];
  const void* Wk  = d_in[7];  const void* bk  = d_in[8];
  const void* Wv  = d_in[9];  const void* bv  = d_in[10];
  const void* W11 = d_in[11]; const void* b11 = d_in[12];
  const void* W12 = d_in[13]; const void* b12 = d_in[14];
  const void* W21 = d_in[15]; const void* b21 = d_in[16];
  const void* W22 = d_in[17]; const void* b22 = d_in[18];

  // fp32 workspace (~33.6 MB). hb [8192,512] overlays qp+kpp (dead post-attn).
  float* ws = (float*)d_ws;
  const size_t SZ = (size_t)Bv * Nv * Cv;        // 2,097,152
  float* qp   = ws;                               // q proj
  float* kpp  = qp + SZ;                          // k proj
  float* vpp  = kpp + SZ;                         // v proj -> later rs2
  float* ao   = vpp + SZ;                         // attn out -> later rs1
  float* hb   = qp;                               // MLP hidden [B*N, 2C] overlay
  float* cent = ao + SZ;                          // [B,K,C]
  float* cnts = cent + Bv * Kv * Cv;              // [B,K]
  int*   flag = (int*)(cnts + Bv * Kv);

  const dim3 blk(256);

  // dtype probe (65536 words is in-bounds for bf16 or fp32 q_img)
  detect_k<<<dim3(1), blk, 0, stream>>>((const unsigned short*)q_img, 65536, flag);

  // projections (BCHW->BNC transpose fused into A load)
  gemm_k<true, true, 0, false><<<dim3(64, 4, 2), blk, 0, stream>>>(
      q_img, Wq, bq, nullptr, qp, Nv, Cv, Cv, (long long)Cv * Nv, (long long)Nv * Cv, flag);
  gemm_k<true, true, 0, false><<<dim3(64, 4, 2), blk, 0, stream>>>(
      k_img, Wk, bk, nullptr, kpp, Nv, Cv, Cv, (long long)Cv * Nv, (long long)Nv * Cv, flag);
  gemm_k<true, true, 0, false><<<dim3(64, 4, 2), blk, 0, stream>>>(
      v_img, Wv, bv, nullptr, vpp, Nv, Cv, Cv, (long long)Cv * Nv, (long long)Nv * Cv, flag);

  // cluster centers (from k projection)
  zero_k<<<dim3(33), blk, 0, stream>>>(cent, Bv * Kv * Cv + Bv * Kv);
  center_accum<<<dim3(Bv * Kv * 8), blk, 0, stream>>>(kpp, labels, cent, cnts);
  center_norm<<<dim3(Bv * Kv * Cv / 256), blk, 0, stream>>>(cent, cnts);

  // attention -> ao
  attn_k<<<dim3(64 * NHv * Bv), blk, 0, stream>>>(qp, kpp, vpp, cent, labels, pc, ao, flag);

  // MLP1: rs1 = v + W12(leaky(W11(ao)))      (hb overlays dead qp/kpp; rs1 -> ao)
  gemm_k<false, false, 1, false><<<dim3(128, 8, 1), blk, 0, stream>>>(
      ao, W11, b11, nullptr, hb, Bv * Nv, 2 * Cv, Cv, 0, 0, flag);
  gemm_k<false, false, 0, true><<<dim3(128, 4, 1), blk, 0, stream>>>(
      hb, W12, b12, vpp, ao, Bv * Nv, Cv, 2 * Cv, 0, 0, flag);

  // MLP2: rs2 = rs1 + W22(leaky(W21(rs1)))   (rs2 -> vpp, dead after MLP1)
  gemm_k<false, false, 1, false><<<dim3(128, 8, 1), blk, 0, stream>>>(
      ao, W21, b21, nullptr, hb, Bv * Nv, 2 * Cv, Cv, 0, 0, flag);
  gemm_k<false, false, 0, true><<<dim3(128, 4, 1), blk, 0, stream>>>(
      hb, W22, b22, ao, vpp, Bv * Nv, Cv, 2 * Cv, 0, 0, flag);

  // [B,N,C] -> [B,C,H,W], dtype per flag
  transpose_k<<<dim3(Nv / 32, Cv / 32, Bv), dim3(32, 8), 0, stream>>>(vpp, d_out, flag);
}

// Round 4
// 711.733 us; speedup vs baseline: 3.9614x; 3.9614x over previous
//
#include <hip/hip_runtime.h>
#include <hip/hip_bf16.h>
#include <stdint.h>

#define Bv 2
#define Cv 256
#define Nv 4096
#define NHv 4
#define HDv 64
#define Kv 16

// R3 established: inputs AND output are fp32 (runtime probe fired f32; passed).
// Probe removed. Attention QK^T/PV now run on bf16 MFMA (error budget ~0.02
// vs 0.062 threshold); GEMMs remain fp32 VALU this round.

typedef __attribute__((ext_vector_type(8))) short bf16x8;
typedef __attribute__((ext_vector_type(4))) float f32x4;

__device__ __forceinline__ float bf2f(unsigned short u) {
  union { unsigned int i; float f; } x; x.i = ((unsigned int)u) << 16; return x.f;
}
__device__ __forceinline__ unsigned short f2bf(float f) {
  union { float f; unsigned int i; } x; x.f = f;
  unsigned int r = x.i + 0x7FFF + ((x.i >> 16) & 1);   // RNE
  return (unsigned short)(r >> 16);
}

// ---------------------------------------------------------------------------
// Tiled fp32 GEMM: C[M,Nn] = act(A[M,Kd] @ Bw[Kd,Nn] + bias) (+ Res)
// A_COL: A element (m,k) at A[k*M + m] (fuses BCHW->BNC transpose).
// ---------------------------------------------------------------------------
template<bool A_COL, int ACT, bool RES>
__global__ __launch_bounds__(256) void gemm_k(
    const float* __restrict__ A, const float* __restrict__ Bw,
    const float* __restrict__ bias, const float* __restrict__ Res,
    float* __restrict__ Cc, int M, int Nn, int Kd,
    long long aBatch, long long cBatch)
{
  __shared__ __align__(16) float As[16][68];
  __shared__ __align__(16) float Bs[16][68];
  const int tid = threadIdx.x;
  const int tx = tid & 15, ty = tid >> 4;
  const int m0 = blockIdx.x * 64, n0 = blockIdx.y * 64;
  const long long ab = (long long)blockIdx.z * aBatch;
  const long long cb = (long long)blockIdx.z * cBatch;

  float acc[4][4];
#pragma unroll
  for (int i = 0; i < 4; ++i)
#pragma unroll
    for (int j = 0; j < 4; ++j) acc[i][j] = 0.f;

  for (int k0 = 0; k0 < Kd; k0 += 16) {
    if (A_COL) {
#pragma unroll
      for (int l = 0; l < 4; ++l) {
        const int idx = tid + l * 256;
        const int m = idx & 63, kk = idx >> 6;
        As[kk][m] = A[ab + (long long)(k0 + kk) * M + (m0 + m)];
      }
    } else {
#pragma unroll
      for (int l = 0; l < 4; ++l) {
        const int idx = tid + l * 256;
        const int kk = idx & 15, m = idx >> 4;
        As[kk][m] = A[ab + (long long)(m0 + m) * Kd + (k0 + kk)];
      }
    }
#pragma unroll
    for (int l = 0; l < 4; ++l) {
      const int idx = tid + l * 256;
      const int n = idx & 63, kk = idx >> 6;
      Bs[kk][n] = Bw[(long long)(k0 + kk) * Nn + (n0 + n)];
    }
    __syncthreads();
#pragma unroll
    for (int kk = 0; kk < 16; ++kk) {
      float av[4], bv[4];
      *(float4*)av = *(const float4*)&As[kk][ty * 4];
      *(float4*)bv = *(const float4*)&Bs[kk][tx * 4];
#pragma unroll
      for (int i = 0; i < 4; ++i)
#pragma unroll
        for (int j = 0; j < 4; ++j) acc[i][j] += av[i] * bv[j];
    }
    __syncthreads();
  }
#pragma unroll
  for (int i = 0; i < 4; ++i) {
    const int row = m0 + ty * 4 + i;
#pragma unroll
    for (int j = 0; j < 4; ++j) {
      const int col = n0 + tx * 4 + j;
      float cv = acc[i][j] + bias[col];
      if (ACT == 1) cv = cv > 0.f ? cv : 0.01f * cv;
      if (RES) cv += Res[cb + (long long)row * Nn + col];
      Cc[cb + (long long)row * Nn + col] = cv;
    }
  }
}

// ---------------------------------------------------------------------------
// Cluster centers
// ---------------------------------------------------------------------------
__global__ __launch_bounds__(256) void zero_k(float* p, int n)
{
  const int i = blockIdx.x * 256 + threadIdx.x;
  if (i < n) p[i] = 0.f;
}

__global__ __launch_bounds__(256) void center_accum(
    const float* __restrict__ kp, const int* __restrict__ labels,
    float* __restrict__ cent, float* __restrict__ cnts)
{
  const int bx = blockIdx.x;           // Bv*Kv*8 blocks
  const int chunk = bx & 7;
  const int kk = (bx >> 3) & 15;
  const int b = bx >> 7;
  const int c = threadIdx.x;
  const int nbase = chunk * (Nv / 8);
  float acc = 0.f;
  int cnt = 0;
  for (int i = 0; i < Nv / 8; ++i) {
    const int n = nbase + i;
    if (labels[b * Nv + n] == kk) {    // wave-uniform branch
      acc += kp[(long long)(b * Nv + n) * Cv + c];
      ++cnt;
    }
  }
  atomicAdd(&cent[(b * Kv + kk) * Cv + c], acc);
  if (c == 0) atomicAdd(&cnts[b * Kv + kk], (float)cnt);
}

__global__ __launch_bounds__(256) void center_norm(float* cent, const float* cnts)
{
  const int i = blockIdx.x * 256 + threadIdx.x;  // Bv*Kv*Cv
  cent[i] = cent[i] / (cnts[i >> 8] + 1e-6f);
}

// ---------------------------------------------------------------------------
// MFMA flash attention. Block = (b,h,qtile of 64 rows), 4 waves, wave w owns
// q-rows w*16..w*16+15. QK^T and PV on mfma_f32_16x16x32_bf16.
// Layouts (verified m89): A frag A[m=lane&15][k=quad*8+j]; B frag
// B[k=quad*8+j][n=lane&15]; C/D: col=lane&15, row=quad*4+reg.
// q/k stored row-major [m][d] bf16 (B-frag for QK needs K[n][k] = row-major);
// v stored transposed [d][m] (B-frag for PV needs V[k][n] with k=m').
// Rows padded 64->72 bf16 (144B stride) -> uniform bank spread on b128 reads.
// P does C->A layout transform via per-wave LDS (same-wave in-order, no
// barrier needed). q pre-scaled by 1/8 so intra and inter (ac*pc) are both
// pre-divided by SCALE, matching the reference's where(...)/SCALE.
// ---------------------------------------------------------------------------
__global__ __launch_bounds__(256) void attn_k(
    const float* __restrict__ qp, const float* __restrict__ kp,
    const float* __restrict__ vp, const float* __restrict__ cent,
    const int* __restrict__ labels, const float* __restrict__ pc,
    float* __restrict__ outp)
{
  __shared__ __align__(16) unsigned short q_s[64][72];
  __shared__ __align__(16) unsigned short k_s[64][72];
  __shared__ __align__(16) unsigned short vt_s[64][72];
  __shared__ __align__(16) unsigned short p_s[4][16][72];
  __shared__ float c_s[16][68];
  __shared__ float ac_s[64][16];
  __shared__ int labq_s[64];
  __shared__ int labm_s[64];

  const int tid = threadIdx.x;
  const int lane = tid & 63;
  const int w = tid >> 6;
  const int lr = lane & 15;
  const int quad = lane >> 4;
  const int bx = blockIdx.x;
  const int qt = bx & 63;
  const int h = (bx >> 6) & 3;
  const int b = bx >> 8;
  const int n0 = qt * 64;

  // stage q (scaled 1/8 -> bf16), labels, centers
#pragma unroll
  for (int i = 0; i < 4; ++i) {
    const int f = tid + i * 256;
    const int r = f >> 4, dq = (f & 15) * 4;
    const float4 qv = *(const float4*)&qp[((long long)(b * Nv + n0 + r)) * Cv + h * HDv + dq];
    const unsigned int lo = f2bf(qv.x * 0.125f) | ((unsigned int)f2bf(qv.y * 0.125f) << 16);
    const unsigned int hi = f2bf(qv.z * 0.125f) | ((unsigned int)f2bf(qv.w * 0.125f) << 16);
    *(uint2*)&q_s[r][dq] = make_uint2(lo, hi);
  }
  if (tid < 64) labq_s[tid] = labels[b * Nv + n0 + tid];
  for (int idx = tid; idx < Kv * HDv; idx += 256) {
    const int kk = idx >> 6, d2 = idx & 63;
    c_s[kk][d2] = cent[((long long)(b * Kv + kk)) * Cv + h * HDv + d2];
  }
  __syncthreads();
  // ac_s[r][k] = (q_r/8) . center_k   (fp32 accumulate from bf16 q)
  for (int idx = tid; idx < 64 * Kv; idx += 256) {
    const int r = idx >> 4, kk = idx & 15;
    float s = 0.f;
#pragma unroll
    for (int d = 0; d < HDv; ++d) s += bf2f(q_s[r][d]) * c_s[kk][d];
    ac_s[r][kk] = s;
  }
  // (ac_s consumers run after the loop's staging barrier -> visible)

  const bf16x8 qa0 = *(const bf16x8*)&q_s[w * 16 + lr][quad * 8];
  const bf16x8 qa1 = *(const bf16x8*)&q_s[w * 16 + lr][32 + quad * 8];

  f32x4 oacc[4];
  float mrow[4], lrow[4];
#pragma unroll
  for (int s2 = 0; s2 < 4; ++s2) oacc[s2] = (f32x4){0.f, 0.f, 0.f, 0.f};
#pragma unroll
  for (int r = 0; r < 4; ++r) { mrow[r] = -1e30f; lrow[r] = 0.f; }

  const int row_l = w * 16 + quad * 4;    // + reg

  for (int m0 = 0; m0 < Nv; m0 += 64) {
    __syncthreads();      // all waves done with k_s/vt_s of previous tile
#pragma unroll
    for (int i = 0; i < 4; ++i) {
      const int f = tid + i * 256;
      const int r = f >> 4, dq = (f & 15) * 4;
      const long long src = ((long long)(b * Nv + m0 + r)) * Cv + h * HDv + dq;
      const float4 kv = *(const float4*)&kp[src];
      const float4 vv = *(const float4*)&vp[src];
      const unsigned int lo = f2bf(kv.x) | ((unsigned int)f2bf(kv.y) << 16);
      const unsigned int hi = f2bf(kv.z) | ((unsigned int)f2bf(kv.w) << 16);
      *(uint2*)&k_s[r][dq] = make_uint2(lo, hi);
      vt_s[dq + 0][r] = f2bf(vv.x);
      vt_s[dq + 1][r] = f2bf(vv.y);
      vt_s[dq + 2][r] = f2bf(vv.z);
      vt_s[dq + 3][r] = f2bf(vv.w);
    }
    if (tid < 64) labm_s[tid] = labels[b * Nv + m0 + tid];
    __syncthreads();

    // QK^T: S[16 rows][64 m'] per wave, 4 subtiles x (2 chained K=32 MFMAs)
    f32x4 sacc[4];
#pragma unroll
    for (int sub = 0; sub < 4; ++sub) {
      const bf16x8 kb0 = *(const bf16x8*)&k_s[sub * 16 + lr][quad * 8];
      const bf16x8 kb1 = *(const bf16x8*)&k_s[sub * 16 + lr][32 + quad * 8];
      f32x4 s = (f32x4){0.f, 0.f, 0.f, 0.f};
      s = __builtin_amdgcn_mfma_f32_16x16x32_bf16(qa0, kb0, s, 0, 0, 0);
      s = __builtin_amdgcn_mfma_f32_16x16x32_bf16(qa1, kb1, s, 0, 0, 0);
      sacc[sub] = s;
    }

    // gather select operands (issue all 16 pc loads up front)
    int labm[4];
#pragma unroll
    for (int sub = 0; sub < 4; ++sub) labm[sub] = labm_s[sub * 16 + lr];
    float pcv[4][4], acv[4][4];
#pragma unroll
    for (int sub = 0; sub < 4; ++sub)
#pragma unroll
      for (int reg = 0; reg < 4; ++reg) {
        pcv[sub][reg] = pc[((long long)(b * Nv + n0 + row_l + reg)) * Nv + m0 + sub * 16 + lr];
        acv[sub][reg] = ac_s[row_l + reg][labm[sub]];
      }

    // adaptive select + online softmax (C-layout: 4 rows/lane, 16 cols/quad)
    float alpha[4], pv[4][4];
#pragma unroll
    for (int reg = 0; reg < 4; ++reg) {
      const int Ln = labq_s[row_l + reg];
      float sv[4];
#pragma unroll
      for (int sub = 0; sub < 4; ++sub)
        sv[sub] = (labm[sub] == Ln) ? sacc[sub][reg] : acv[sub][reg] * pcv[sub][reg];
      float mx = fmaxf(fmaxf(sv[0], sv[1]), fmaxf(sv[2], sv[3]));
      mx = fmaxf(mx, __shfl_xor(mx, 1));
      mx = fmaxf(mx, __shfl_xor(mx, 2));
      mx = fmaxf(mx, __shfl_xor(mx, 4));
      mx = fmaxf(mx, __shfl_xor(mx, 8));
      const float mn = fmaxf(mrow[reg], mx);
      const float a = __expf(mrow[reg] - mn);
      float ps = 0.f;
#pragma unroll
      for (int sub = 0; sub < 4; ++sub) { pv[sub][reg] = __expf(sv[sub] - mn); ps += pv[sub][reg]; }
      ps += __shfl_xor(ps, 1);
      ps += __shfl_xor(ps, 2);
      ps += __shfl_xor(ps, 4);
      ps += __shfl_xor(ps, 8);
      lrow[reg] = lrow[reg] * a + ps;
      mrow[reg] = mn;
      alpha[reg] = a;
    }

    // P: C-layout -> A-layout via per-wave LDS; rescale O
#pragma unroll
    for (int sub = 0; sub < 4; ++sub)
#pragma unroll
      for (int reg = 0; reg < 4; ++reg) {
        p_s[w][quad * 4 + reg][sub * 16 + lr] = f2bf(pv[sub][reg]);
        oacc[sub][reg] *= alpha[reg];
      }

    // PV (same-wave LDS in-order: writes above precede these reads)
    const bf16x8 pa0 = *(const bf16x8*)&p_s[w][lr][quad * 8];
    const bf16x8 pa1 = *(const bf16x8*)&p_s[w][lr][32 + quad * 8];
#pragma unroll
    for (int sub = 0; sub < 4; ++sub) {
      const bf16x8 vb0 = *(const bf16x8*)&vt_s[sub * 16 + lr][quad * 8];
      const bf16x8 vb1 = *(const bf16x8*)&vt_s[sub * 16 + lr][32 + quad * 8];
      oacc[sub] = __builtin_amdgcn_mfma_f32_16x16x32_bf16(pa0, vb0, oacc[sub], 0, 0, 0);
      oacc[sub] = __builtin_amdgcn_mfma_f32_16x16x32_bf16(pa1, vb1, oacc[sub], 0, 0, 0);
    }
  }

  // epilogue: O /= l
#pragma unroll
  for (int reg = 0; reg < 4; ++reg) {
    const float inv = 1.f / lrow[reg];
    const long long base = ((long long)(b * Nv + n0 + row_l + reg)) * Cv + h * HDv;
#pragma unroll
    for (int sub = 0; sub < 4; ++sub)
      outp[base + sub * 16 + lr] = oacc[sub][reg] * inv;
  }
}

// ---------------------------------------------------------------------------
// [B,N,C] fp32 -> [B,C,N] fp32 output transpose
// ---------------------------------------------------------------------------
__global__ __launch_bounds__(256) void transpose_k(const float* __restrict__ in,
                                                   float* __restrict__ out)
{
  __shared__ float t[32][33];
  const int x = threadIdx.x;   // 32
  const int y = threadIdx.y;   // 8
  const int n0 = blockIdx.x * 32, c0 = blockIdx.y * 32, b = blockIdx.z;
  for (int i = y; i < 32; i += 8)
    t[i][x] = in[(long long)(b * Nv + n0 + i) * Cv + c0 + x];
  __syncthreads();
  for (int i = y; i < 32; i += 8)
    out[(long long)(b * Cv + c0 + i) * Nv + n0 + x] = t[x][i];
}

// ---------------------------------------------------------------------------
extern "C" void kernel_launch(void* const* d_in, const int* in_sizes, int n_in,
                              void* d_out, int out_size, void* d_ws, size_t ws_size,
                              hipStream_t stream)
{
  const float* q_img = (const float*)d_in[0];
  const float* k_img = (const float*)d_in[1];
  const float* v_img = (const float*)d_in[2];
  const int* labels  = (const int*)d_in[3];
  const float* pc    = (const float*)d_in[4];
  const float* Wq  = (const float*)d_in[5];  const float* bq  = (const float*)d_in[6];
  const float* Wk  = (const float*)d_in[7];  const float* bk  = (const float*)d_in[8];
  const float* Wv  = (const float*)d_in[9];  const float* bv  = (const float*)d_in[10];
  const float* W11 = (const float*)d_in[11]; const float* b11 = (const float*)d_in[12];
  const float* W12 = (const float*)d_in[13]; const float* b12 = (const float*)d_in[14];
  const float* W21 = (const float*)d_in[15]; const float* b21 = (const float*)d_in[16];
  const float* W22 = (const float*)d_in[17]; const float* b22 = (const float*)d_in[18];
  float* outp = (float*)d_out;

  // fp32 workspace (~33.6 MB). hb [8192,512] overlays qp+kpp (dead post-attn).
  float* ws = (float*)d_ws;
  const size_t SZ = (size_t)Bv * Nv * Cv;        // 2,097,152
  float* qp   = ws;                               // q proj
  float* kpp  = qp + SZ;                          // k proj
  float* vpp  = kpp + SZ;                         // v proj -> later rs2
  float* ao   = vpp + SZ;                         // attn out -> later rs1
  float* hb   = qp;                               // MLP hidden [B*N, 2C] overlay
  float* cent = ao + SZ;                          // [B,K,C]
  float* cnts = cent + Bv * Kv * Cv;              // [B,K]

  const dim3 blk(256);

  // projections (BCHW->BNC transpose fused into A load)
  gemm_k<true, 0, false><<<dim3(64, 4, 2), blk, 0, stream>>>(
      q_img, Wq, bq, nullptr, qp, Nv, Cv, Cv, (long long)Cv * Nv, (long long)Nv * Cv);
  gemm_k<true, 0, false><<<dim3(64, 4, 2), blk, 0, stream>>>(
      k_img, Wk, bk, nullptr, kpp, Nv, Cv, Cv, (long long)Cv * Nv, (long long)Nv * Cv);
  gemm_k<true, 0, false><<<dim3(64, 4, 2), blk, 0, stream>>>(
      v_img, Wv, bv, nullptr, vpp, Nv, Cv, Cv, (long long)Cv * Nv, (long long)Nv * Cv);

  // cluster centers (from k projection)
  zero_k<<<dim3(33), blk, 0, stream>>>(cent, Bv * Kv * Cv + Bv * Kv);
  center_accum<<<dim3(Bv * Kv * 8), blk, 0, stream>>>(kpp, labels, cent, cnts);
  center_norm<<<dim3(Bv * Kv * Cv / 256), blk, 0, stream>>>(cent, cnts);

  // attention -> ao
  attn_k<<<dim3(64 * NHv * Bv), blk, 0, stream>>>(qp, kpp, vpp, cent, labels, pc, ao);

  // MLP1: rs1 = v + W12(leaky(W11(ao)))      (hb overlays dead qp/kpp; rs1 -> ao)
  gemm_k<false, 1, false><<<dim3(128, 8, 1), blk, 0, stream>>>(
      ao, W11, b11, nullptr, hb, Bv * Nv, 2 * Cv, Cv, 0, 0);
  gemm_k<false, 0, true><<<dim3(128, 4, 1), blk, 0, stream>>>(
      hb, W12, b12, vpp, ao, Bv * Nv, Cv, 2 * Cv, 0, 0);

  // MLP2: rs2 = rs1 + W22(leaky(W21(rs1)))   (rs2 -> vpp, dead after MLP1)
  gemm_k<false, 1, false><<<dim3(128, 8, 1), blk, 0, stream>>>(
      ao, W21, b21, nullptr, hb, Bv * Nv, 2 * Cv, Cv, 0, 0);
  gemm_k<false, 0, true><<<dim3(128, 4, 1), blk, 0, stream>>>(
      hb, W22, b22, ao, vpp, Bv * Nv, Cv, 2 * Cv, 0, 0);

  // [B,N,C] -> [B,C,H,W] fp32
  transpose_k<<<dim3(Nv / 32, Cv / 32, Bv), dim3(32, 8), 0, stream>>>(vpp, outp);
}

// Round 5
// 482.519 us; speedup vs baseline: 5.8432x; 1.4750x over previous
//
#include <hip/hip_runtime.h>
#include <stdint.h>

#define Bv 2
#define Cv 256
#define Nv 4096
#define NHv 4
#define HDv 64
#define Kv 16

// R3: inputs & output fp32. R4: bf16-MFMA attention passed (absmax 0.0156).
// R5: bf16-MFMA everything; fixed-max softmax; conflict-free LDS layouts.

typedef __attribute__((ext_vector_type(8))) short bf16x8;
typedef __attribute__((ext_vector_type(4))) short bf16x4;
typedef __attribute__((ext_vector_type(4))) float f32x4;

__device__ __forceinline__ float bf2f(unsigned short u) {
  union { unsigned int i; float f; } x; x.i = ((unsigned int)u) << 16; return x.f;
}
__device__ __forceinline__ unsigned short f2bf(float f) {
  union { float f; unsigned int i; } x; x.f = f;
  unsigned int r = x.i + 0x7FFF + ((x.i >> 16) & 1);   // RNE
  return (unsigned short)(r >> 16);
}

// ---------------------------------------------------------------------------
// Prep 1: img [b][c][n] fp32 -> imgT [z][n][c] bf16  (z = img*2 + b, z<6)
// ---------------------------------------------------------------------------
__global__ __launch_bounds__(256) void imgt_k(
    const float* __restrict__ qi, const float* __restrict__ ki,
    const float* __restrict__ vi, unsigned short* __restrict__ dst)
{
  const int z = blockIdx.z;
  const float* src = (z < 2 ? qi : (z < 4 ? ki : vi)) + (long long)(z & 1) * Cv * Nv;
  unsigned short* out = dst + (long long)z * Nv * Cv;
  __shared__ float t[32][33];
  const int x = threadIdx.x, y = threadIdx.y;
  const int n0 = blockIdx.x * 32, c0 = blockIdx.y * 32;
  for (int i = y; i < 32; i += 8)
    t[i][x] = src[(long long)(c0 + i) * Nv + n0 + x];
  __syncthreads();
  for (int i = y; i < 32; i += 8)
    out[(long long)(n0 + i) * Cv + c0 + x] = f2bf(t[x][i]);
}

// ---------------------------------------------------------------------------
// Prep 2: W [k][n] fp32 -> Wt [n][k] bf16, 7 weights packed into one buffer
// ---------------------------------------------------------------------------
struct WP { const float* p[7]; };

__global__ __launch_bounds__(256) void wt_k(WP wp, unsigned short* __restrict__ dst)
{
  const int z = blockIdx.z;
  const int KD[7] = {256, 256, 256, 256, 512, 256, 512};
  const int ND[7] = {256, 256, 256, 512, 256, 512, 256};
  const long long OFF[7] = {0, 65536, 131072, 196608, 327680, 458752, 589824};
  const int Kw = KD[z], Nw = ND[z];
  const int nb = blockIdx.x * 32, kb2 = blockIdx.y * 32;
  if (nb >= Nw || kb2 >= Kw) return;
  __shared__ float t[32][33];
  const int x = threadIdx.x, y = threadIdx.y;
  const float* src = wp.p[z];
  for (int i = y; i < 32; i += 8)
    t[i][x] = src[(long long)(kb2 + i) * Nw + nb + x];
  __syncthreads();
  for (int i = y; i < 32; i += 8)
    dst[OFF[z] + (long long)(nb + i) * Kw + kb2 + x] = f2bf(t[x][i]);
}

// ---------------------------------------------------------------------------
// bf16 MFMA GEMM, 128x128 tile, BK=64, 4 waves x (4x4 16x16 frags).
// A: [z][M][K] (bf16 if ABF16 else fp32, k-contiguous). Bt: bf16 [N][K].
// OM: 0 fp32 [m][n]; 1 bf16 [m][n]; 2 bf16 [m][n] *0.125 (q);
//     3 fp32 [m][n] + bf16 transposed [n][m-within-batch] (v);
//     4 fp32 transposed to [B][C][N] from flattened m (final output).
// ---------------------------------------------------------------------------
template<bool ABF16, int ACT, int RES, int OM>
__global__ __launch_bounds__(256) void mm_k(
    const void* __restrict__ A, const unsigned short* __restrict__ Bt,
    const float* __restrict__ bias, const float* __restrict__ Res,
    float* __restrict__ outF, unsigned short* __restrict__ outB,
    int M, int Nn, int Kd, long long aBatch, long long oBatch, long long obBatch)
{
  __shared__ __align__(16) unsigned short As[128][72];
  __shared__ __align__(16) unsigned short Bs[128][72];
  const int tid = threadIdx.x;
  const int w = tid >> 6, lane = tid & 63;
  const int lr = lane & 15, quad = lane >> 4;
  const int m0 = blockIdx.x * 128, n0 = blockIdx.y * 128;
  const int z = blockIdx.z;
  const int wm = (w >> 1) * 64, wn = (w & 1) * 64;
  const int sr = tid >> 1, sh = (tid & 1) * 32;

  f32x4 acc[4][4];
#pragma unroll
  for (int i = 0; i < 4; ++i)
#pragma unroll
    for (int j = 0; j < 4; ++j) acc[i][j] = (f32x4){0.f, 0.f, 0.f, 0.f};

  const long long abase = (long long)z * aBatch + (long long)(m0 + sr) * Kd + sh;
  const unsigned short* Bb = Bt + (long long)(n0 + sr) * Kd + sh;

  for (int k0 = 0; k0 < Kd; k0 += 64) {
    if (ABF16) {
      const unsigned short* Ab = (const unsigned short*)A + abase + k0;
      uint4 u0 = *(const uint4*)Ab;
      uint4 u1 = *(const uint4*)(Ab + 8);
      uint4 u2 = *(const uint4*)(Ab + 16);
      uint4 u3 = *(const uint4*)(Ab + 24);
      *(uint4*)&As[sr][sh] = u0;
      *(uint4*)&As[sr][sh + 8] = u1;
      *(uint4*)&As[sr][sh + 16] = u2;
      *(uint4*)&As[sr][sh + 24] = u3;
    } else {
      const float* Af = (const float*)A + abase + k0;
#pragma unroll
      for (int t = 0; t < 4; ++t) {
        const float4 f0 = *(const float4*)(Af + t * 8);
        const float4 f1 = *(const float4*)(Af + t * 8 + 4);
        uint4 pk;
        pk.x = f2bf(f0.x) | ((unsigned int)f2bf(f0.y) << 16);
        pk.y = f2bf(f0.z) | ((unsigned int)f2bf(f0.w) << 16);
        pk.z = f2bf(f1.x) | ((unsigned int)f2bf(f1.y) << 16);
        pk.w = f2bf(f1.z) | ((unsigned int)f2bf(f1.w) << 16);
        *(uint4*)&As[sr][sh + t * 8] = pk;
      }
    }
    {
      const unsigned short* Bp = Bb + k0;
      uint4 u0 = *(const uint4*)Bp;
      uint4 u1 = *(const uint4*)(Bp + 8);
      uint4 u2 = *(const uint4*)(Bp + 16);
      uint4 u3 = *(const uint4*)(Bp + 24);
      *(uint4*)&Bs[sr][sh] = u0;
      *(uint4*)&Bs[sr][sh + 8] = u1;
      *(uint4*)&Bs[sr][sh + 16] = u2;
      *(uint4*)&Bs[sr][sh + 24] = u3;
    }
    __syncthreads();
#pragma unroll
    for (int ks = 0; ks < 2; ++ks) {
      bf16x8 af[4], bfr[4];
#pragma unroll
      for (int i = 0; i < 4; ++i)
        af[i] = *(const bf16x8*)&As[wm + i * 16 + lr][ks * 32 + quad * 8];
#pragma unroll
      for (int j = 0; j < 4; ++j)
        bfr[j] = *(const bf16x8*)&Bs[wn + j * 16 + lr][ks * 32 + quad * 8];
#pragma unroll
      for (int i = 0; i < 4; ++i)
#pragma unroll
        for (int j = 0; j < 4; ++j)
          acc[i][j] = __builtin_amdgcn_mfma_f32_16x16x32_bf16(af[i], bfr[j], acc[i][j], 0, 0, 0);
    }
    __syncthreads();
  }

#pragma unroll
  for (int j = 0; j < 4; ++j) {
    const int col = n0 + wn + j * 16 + lr;
    const float bv = bias[col];
#pragma unroll
    for (int i = 0; i < 4; ++i) {
      const int mb = m0 + wm + i * 16 + quad * 4;
      float r[4];
#pragma unroll
      for (int reg = 0; reg < 4; ++reg) {
        float v = acc[i][j][reg] + bv;
        if (ACT) v = v > 0.f ? v : 0.01f * v;
        if (RES) v += Res[(long long)(mb + reg) * Nn + col];
        r[reg] = v;
      }
      if (OM == 0) {
#pragma unroll
        for (int reg = 0; reg < 4; ++reg)
          outF[(long long)z * oBatch + (long long)(mb + reg) * Nn + col] = r[reg];
      } else if (OM == 1) {
#pragma unroll
        for (int reg = 0; reg < 4; ++reg)
          outB[(long long)z * obBatch + (long long)(mb + reg) * Nn + col] = f2bf(r[reg]);
      } else if (OM == 2) {
#pragma unroll
        for (int reg = 0; reg < 4; ++reg)
          outB[(long long)z * obBatch + (long long)(mb + reg) * Nn + col] = f2bf(r[reg] * 0.125f);
      } else if (OM == 3) {
#pragma unroll
        for (int reg = 0; reg < 4; ++reg)
          outF[(long long)z * oBatch + (long long)(mb + reg) * Nn + col] = r[reg];
        uint2 pk;
        pk.x = f2bf(r[0]) | ((unsigned int)f2bf(r[1]) << 16);
        pk.y = f2bf(r[2]) | ((unsigned int)f2bf(r[3]) << 16);
        *(uint2*)&outB[(long long)z * obBatch + (long long)col * Nv + mb] = pk;
      } else {  // OM == 4: fp32 transposed to [B][C][N], m flattened over (b,n)
        const float4 st = {r[0], r[1], r[2], r[3]};
        *(float4*)&outF[((long long)((mb >> 12) * Cv + col)) * Nv + (mb & 4095)] = st;
      }
    }
  }
}

// ---------------------------------------------------------------------------
// Cluster centers (from bf16 k projection)
// ---------------------------------------------------------------------------
__global__ __launch_bounds__(256) void zero_k(float* p, int n)
{
  const int i = blockIdx.x * 256 + threadIdx.x;
  if (i < n) p[i] = 0.f;
}

__global__ __launch_bounds__(256) void center_accum(
    const unsigned short* __restrict__ kb, const int* __restrict__ labels,
    float* __restrict__ cent, float* __restrict__ cnts)
{
  const int bx = blockIdx.x;           // Bv*Kv*8 blocks
  const int chunk = bx & 7;
  const int kk = (bx >> 3) & 15;
  const int b = bx >> 7;
  const int c = threadIdx.x;
  const int nbase = chunk * (Nv / 8);
  float acc = 0.f;
  int cnt = 0;
  for (int i = 0; i < Nv / 8; ++i) {
    const int n = nbase + i;
    if (labels[b * Nv + n] == kk) {    // wave-uniform branch
      acc += bf2f(kb[(long long)(b * Nv + n) * Cv + c]);
      ++cnt;
    }
  }
  atomicAdd(&cent[(b * Kv + kk) * Cv + c], acc);
  if (c == 0) atomicAdd(&cnts[b * Kv + kk], (float)cnt);
}

__global__ __launch_bounds__(256) void center_norm(float* cent, const float* cnts)
{
  const int i = blockIdx.x * 256 + threadIdx.x;  // Bv*Kv*Cv
  cent[i] = cent[i] / (cnts[i >> 8] + 1e-6f);
}

// ---------------------------------------------------------------------------
// MFMA flash attention, fixed-max softmax (m=4; scores bounded |s|<72 so
// exp(s-4) cannot overflow; softmax is shift-invariant so result is exact).
// Inputs pre-formatted by projection epilogues:
//   qb [b][n][c] bf16, pre-scaled 1/8;  kb [b][n][c] bf16;
//   vtb [b][c][n] bf16 (transposed -> row-major LDS staging, no conflicts).
// p_s stride 68 shorts: b16 writes ~2-way (free), b64 frag reads aligned.
// Output: aob bf16 [b][n][c].
// ---------------------------------------------------------------------------
__global__ __launch_bounds__(256) void attn_k(
    const unsigned short* __restrict__ qb, const unsigned short* __restrict__ kb,
    const unsigned short* __restrict__ vtb, const float* __restrict__ cent,
    const int* __restrict__ labels, const float* __restrict__ pc,
    unsigned short* __restrict__ outb)
{
  __shared__ __align__(16) unsigned short q_s[64][72];
  __shared__ __align__(16) unsigned short k_s[64][72];
  __shared__ __align__(16) unsigned short vt_s[64][72];
  __shared__ __align__(16) unsigned short p_s[4][16][68];
  __shared__ float c_s[16][68];
  __shared__ float ac_s[64][17];
  __shared__ int labq_s[64], labm_s[64];

  const int tid = threadIdx.x;
  const int lane = tid & 63, w = tid >> 6;
  const int lr = lane & 15, quad = lane >> 4;
  const int bx = blockIdx.x;
  const int qt = bx & 63, h = (bx >> 6) & 3, b = bx >> 8;
  const int n0 = qt * 64;
  const int sr2 = tid >> 2, so2 = (tid & 3) * 16;

  {
    const unsigned short* src = qb + ((long long)(b * Nv + n0 + sr2)) * Cv + h * HDv + so2;
    *(uint4*)&q_s[sr2][so2] = *(const uint4*)src;
    *(uint4*)&q_s[sr2][so2 + 8] = *(const uint4*)(src + 8);
  }
  if (tid < 64) labq_s[tid] = labels[b * Nv + n0 + tid];
  for (int idx = tid; idx < Kv * HDv; idx += 256)
    c_s[idx >> 6][idx & 63] = cent[((long long)(b * Kv + (idx >> 6))) * Cv + h * HDv + (idx & 63)];
  __syncthreads();
  // ac_s[r][k] = (q_r/8) . center_k  (once per block; amortized over 64 tiles)
  for (int idx = tid; idx < 64 * Kv; idx += 256) {
    const int r = idx >> 4, kk = idx & 15;
    float s = 0.f;
#pragma unroll
    for (int d = 0; d < HDv; ++d) s += bf2f(q_s[r][d]) * c_s[kk][d];
    ac_s[r][kk] = s;
  }

  const bf16x8 qa0 = *(const bf16x8*)&q_s[w * 16 + lr][quad * 8];
  const bf16x8 qa1 = *(const bf16x8*)&q_s[w * 16 + lr][32 + quad * 8];

  f32x4 oacc[4];
#pragma unroll
  for (int s2 = 0; s2 < 4; ++s2) oacc[s2] = (f32x4){0.f, 0.f, 0.f, 0.f};
  float lrow[4] = {0.f, 0.f, 0.f, 0.f};
  const int row_l = w * 16 + quad * 4;
  const long long pcb = (long long)b * Nv * Nv;

  for (int m0 = 0; m0 < Nv; m0 += 64) {
    __syncthreads();   // k_s/vt_s of previous tile fully consumed (+ ac_s vis)
    {
      const unsigned short* ksrc = kb + ((long long)(b * Nv + m0 + sr2)) * Cv + h * HDv + so2;
      *(uint4*)&k_s[sr2][so2] = *(const uint4*)ksrc;
      *(uint4*)&k_s[sr2][so2 + 8] = *(const uint4*)(ksrc + 8);
      const unsigned short* vsrc = vtb + ((long long)(b * Cv + h * HDv + sr2)) * Nv + m0 + so2;
      *(uint4*)&vt_s[sr2][so2] = *(const uint4*)vsrc;
      *(uint4*)&vt_s[sr2][so2 + 8] = *(const uint4*)(vsrc + 8);
    }
    if (tid < 64) labm_s[tid] = labels[b * Nv + m0 + tid];
    __syncthreads();

    // QK^T: S[16 q-rows][64 m'] per wave
    f32x4 sacc[4];
#pragma unroll
    for (int sub = 0; sub < 4; ++sub) {
      const bf16x8 kb0 = *(const bf16x8*)&k_s[sub * 16 + lr][quad * 8];
      const bf16x8 kb1 = *(const bf16x8*)&k_s[sub * 16 + lr][32 + quad * 8];
      f32x4 s = (f32x4){0.f, 0.f, 0.f, 0.f};
      s = __builtin_amdgcn_mfma_f32_16x16x32_bf16(qa0, kb0, s, 0, 0, 0);
      s = __builtin_amdgcn_mfma_f32_16x16x32_bf16(qa1, kb1, s, 0, 0, 0);
      sacc[sub] = s;
    }

    int labm[4];
#pragma unroll
    for (int sub = 0; sub < 4; ++sub) labm[sub] = labm_s[sub * 16 + lr];
    float pcv[4][4], acv[4][4];
#pragma unroll
    for (int sub = 0; sub < 4; ++sub)
#pragma unroll
      for (int reg = 0; reg < 4; ++reg) {
        pcv[sub][reg] = pc[pcb + (long long)(n0 + row_l + reg) * Nv + m0 + sub * 16 + lr];
        acv[sub][reg] = ac_s[row_l + reg][labm[sub]];
      }

    // adaptive select + exp (fixed max), accumulate denominator per lane
#pragma unroll
    for (int reg = 0; reg < 4; ++reg) {
      const int Ln = labq_s[row_l + reg];
#pragma unroll
      for (int sub = 0; sub < 4; ++sub) {
        const float s = (labm[sub] == Ln) ? sacc[sub][reg] : acv[sub][reg] * pcv[sub][reg];
        const float p = __expf(s - 4.0f);
        lrow[reg] += p;
        p_s[w][quad * 4 + reg][sub * 16 + lr] = f2bf(p);
      }
    }

    // P A-frags (same-wave in-order LDS; b64 reads, 8B aligned)
    const bf16x4 p00 = *(const bf16x4*)&p_s[w][lr][quad * 8];
    const bf16x4 p01 = *(const bf16x4*)&p_s[w][lr][quad * 8 + 4];
    const bf16x4 p10 = *(const bf16x4*)&p_s[w][lr][32 + quad * 8];
    const bf16x4 p11 = *(const bf16x4*)&p_s[w][lr][32 + quad * 8 + 4];
    const bf16x8 pa0 = __builtin_shufflevector(p00, p01, 0, 1, 2, 3, 4, 5, 6, 7);
    const bf16x8 pa1 = __builtin_shufflevector(p10, p11, 0, 1, 2, 3, 4, 5, 6, 7);
#pragma unroll
    for (int sub = 0; sub < 4; ++sub) {
      const bf16x8 vb0 = *(const bf16x8*)&vt_s[sub * 16 + lr][quad * 8];
      const bf16x8 vb1 = *(const bf16x8*)&vt_s[sub * 16 + lr][32 + quad * 8];
      oacc[sub] = __builtin_amdgcn_mfma_f32_16x16x32_bf16(pa0, vb0, oacc[sub], 0, 0, 0);
      oacc[sub] = __builtin_amdgcn_mfma_f32_16x16x32_bf16(pa1, vb1, oacc[sub], 0, 0, 0);
    }
  }

  // epilogue: reduce l across the 16 lanes sharing each row, store bf16
#pragma unroll
  for (int reg = 0; reg < 4; ++reg) {
    float l = lrow[reg];
    l += __shfl_xor(l, 1); l += __shfl_xor(l, 2);
    l += __shfl_xor(l, 4); l += __shfl_xor(l, 8);
    const float inv = 1.f / l;
    const long long base = ((long long)(b * Nv + n0 + row_l + reg)) * Cv + h * HDv;
#pragma unroll
    for (int sub = 0; sub < 4; ++sub)
      outb[base + sub * 16 + lr] = f2bf(oacc[sub][reg] * inv);
  }
}

// ---------------------------------------------------------------------------
extern "C" void kernel_launch(void* const* d_in, const int* in_sizes, int n_in,
                              void* d_out, int out_size, void* d_ws, size_t ws_size,
                              hipStream_t stream)
{
  const float* q_img = (const float*)d_in[0];
  const float* k_img = (const float*)d_in[1];
  const float* v_img = (const float*)d_in[2];
  const int* labels  = (const int*)d_in[3];
  const float* pc    = (const float*)d_in[4];
  const float* Wq  = (const float*)d_in[5];  const float* bq  = (const float*)d_in[6];
  const float* Wk  = (const float*)d_in[7];  const float* bk  = (const float*)d_in[8];
  const float* Wv  = (const float*)d_in[9];  const float* bv  = (const float*)d_in[10];
  const float* W11 = (const float*)d_in[11]; const float* b11 = (const float*)d_in[12];
  const float* W12 = (const float*)d_in[13]; const float* b12 = (const float*)d_in[14];
  const float* W21 = (const float*)d_in[15]; const float* b21 = (const float*)d_in[16];
  const float* W22 = (const float*)d_in[17]; const float* b22 = (const float*)d_in[18];
  float* outp = (float*)d_out;

  const long long SZ = (long long)Bv * Nv * Cv;     // 2,097,152
  // fp32 region (~16.8 MB)
  float* ws   = (float*)d_ws;
  float* vpp  = ws;                    // v proj fp32 [2][4096][256]
  float* rs1  = vpp + SZ;              // MLP1 out fp32
  float* cent = rs1 + SZ;              // [2][16][256]
  float* cnts = cent + Bv * Kv * Cv;   // [2][16]
  // bf16 region (~26.6 MB)
  unsigned short* wt   = (unsigned short*)(cnts + Bv * Kv);
  unsigned short* qbf  = wt + 720896;  // [2][4096][256] pre-scaled
  unsigned short* kbf  = qbf + SZ;
  unsigned short* vtb  = kbf + SZ;     // [2][256][4096]
  unsigned short* aob  = vtb + SZ;     // attn out bf16
  unsigned short* h1b  = aob + SZ;     // MLP hidden bf16 [8192][512]
  unsigned short* imgT = aob;          // overlay: 6M shorts over aob+h1b (dead then)

  const long long NvCv = (long long)Nv * Cv;

  // prep: transposes + bf16 casts
  imgt_k<<<dim3(Nv / 32, Cv / 32, 6), dim3(32, 8), 0, stream>>>(q_img, k_img, v_img, imgT);
  WP wp = {{Wq, Wk, Wv, W11, W12, W21, W22}};
  wt_k<<<dim3(16, 16, 7), dim3(32, 8), 0, stream>>>(wp, wt);

  // projections (MFMA): q -> qbf (scaled), k -> kbf, v -> vpp + vtb
  mm_k<true, 0, 0, 2><<<dim3(32, 2, 2), 256, 0, stream>>>(
      imgT, wt, bq, nullptr, nullptr, qbf, Nv, Cv, Cv, NvCv, 0, NvCv);
  mm_k<true, 0, 0, 1><<<dim3(32, 2, 2), 256, 0, stream>>>(
      imgT + 2 * NvCv, wt + 65536, bk, nullptr, nullptr, kbf, Nv, Cv, Cv, NvCv, 0, NvCv);
  mm_k<true, 0, 0, 3><<<dim3(32, 2, 2), 256, 0, stream>>>(
      imgT + 4 * NvCv, wt + 131072, bv, nullptr, vpp, vtb, Nv, Cv, Cv, NvCv, NvCv, NvCv);

  // cluster centers
  zero_k<<<dim3(33), 256, 0, stream>>>(cent, Bv * Kv * Cv + Bv * Kv);
  center_accum<<<dim3(Bv * Kv * 8), 256, 0, stream>>>(kbf, labels, cent, cnts);
  center_norm<<<dim3(Bv * Kv * Cv / 256), 256, 0, stream>>>(cent, cnts);

  // attention -> aob (bf16)
  attn_k<<<dim3(64 * NHv * Bv), 256, 0, stream>>>(qbf, kbf, vtb, cent, labels, pc, aob);

  // MLP1: h1 = leaky(aob@W11+b11) bf16 ; rs1 = vpp + h1@W12+b12 (fp32)
  mm_k<true, 1, 0, 1><<<dim3(64, 4, 1), 256, 0, stream>>>(
      aob, wt + 196608, b11, nullptr, nullptr, h1b, 2 * Nv, 2 * Cv, Cv, 0, 0, 0);
  mm_k<true, 0, 1, 0><<<dim3(64, 2, 1), 256, 0, stream>>>(
      h1b, wt + 327680, b12, vpp, rs1, nullptr, 2 * Nv, Cv, 2 * Cv, 0, 0, 0);

  // MLP2: h2 = leaky(rs1@W21+b21) bf16 ; out = rs1 + h2@W22+b22, transposed
  mm_k<false, 1, 0, 1><<<dim3(64, 4, 1), 256, 0, stream>>>(
      rs1, wt + 458752, b21, nullptr, nullptr, h1b, 2 * Nv, 2 * Cv, Cv, 0, 0, 0);
  mm_k<true, 0, 1, 4><<<dim3(64, 2, 1), 256, 0, stream>>>(
      h1b, wt + 589824, b22, rs1, outp, nullptr, 2 * Nv, Cv, 2 * Cv, 0, 0, 0);
}

// Round 6
// 450.296 us; speedup vs baseline: 6.2614x; 1.0716x over previous
//
#include <hip/hip_runtime.h>
#include <stdint.h>

#define Bv 2
#define Cv 256
#define Nv 4096
#define NHv 4
#define HDv 64
#define Kv 16

// R3: inputs/output fp32. R4: bf16 MFMA attention. R5: bf16 MFMA everywhere,
// fixed-max softmax. R6: attn split-m x2 (1024 blocks, 4/CU via 40KB LDS),
// k/v/pc register prefetch pipeline, fused projections, LDS-label centers.

typedef __attribute__((ext_vector_type(8))) short bf16x8;
typedef __attribute__((ext_vector_type(4))) float f32x4;

__device__ __forceinline__ float bf2f(unsigned short u) {
  union { unsigned int i; float f; } x; x.i = ((unsigned int)u) << 16; return x.f;
}
__device__ __forceinline__ unsigned short f2bf(float f) {
  union { float f; unsigned int i; } x; x.f = f;
  unsigned int r = x.i + 0x7FFF + ((x.i >> 16) & 1);   // RNE
  return (unsigned short)(r >> 16);
}

// ---------------------------------------------------------------------------
// Prep 1: img [b][c][n] fp32 -> imgT [z][n][c] bf16  (z = img*2 + b, z<6)
// ---------------------------------------------------------------------------
__global__ __launch_bounds__(256) void imgt_k(
    const float* __restrict__ qi, const float* __restrict__ ki,
    const float* __restrict__ vi, unsigned short* __restrict__ dst)
{
  const int z = blockIdx.z;
  const float* src = (z < 2 ? qi : (z < 4 ? ki : vi)) + (long long)(z & 1) * Cv * Nv;
  unsigned short* out = dst + (long long)z * Nv * Cv;
  __shared__ float t[32][33];
  const int x = threadIdx.x, y = threadIdx.y;
  const int n0 = blockIdx.x * 32, c0 = blockIdx.y * 32;
  for (int i = y; i < 32; i += 8)
    t[i][x] = src[(long long)(c0 + i) * Nv + n0 + x];
  __syncthreads();
  for (int i = y; i < 32; i += 8)
    out[(long long)(n0 + i) * Cv + c0 + x] = f2bf(t[x][i]);
}

// ---------------------------------------------------------------------------
// Prep 2: W [k][n] fp32 -> Wt [n][k] bf16, 7 weights packed into one buffer
// ---------------------------------------------------------------------------
struct WP { const float* p[7]; };

__global__ __launch_bounds__(256) void wt_k(WP wp, unsigned short* __restrict__ dst)
{
  const int z = blockIdx.z;
  const int KD[7] = {256, 256, 256, 256, 512, 256, 512};
  const int ND[7] = {256, 256, 256, 512, 256, 512, 256};
  const long long OFF[7] = {0, 65536, 131072, 196608, 327680, 458752, 589824};
  const int Kw = KD[z], Nw = ND[z];
  const int nb = blockIdx.x * 32, kb2 = blockIdx.y * 32;
  if (nb >= Nw || kb2 >= Kw) return;
  __shared__ float t[32][33];
  const int x = threadIdx.x, y = threadIdx.y;
  const float* src = wp.p[z];
  for (int i = y; i < 32; i += 8)
    t[i][x] = src[(long long)(kb2 + i) * Nw + nb + x];
  __syncthreads();
  for (int i = y; i < 32; i += 8)
    dst[OFF[z] + (long long)(nb + i) * Kw + kb2 + x] = f2bf(t[x][i]);
}

// ---------------------------------------------------------------------------
// Fused q/k/v projection: one dispatch, z = proj*2 + b (z<6).
// 128x128 tile, BK=64. Epilogue per proj: q->qbf(*0.125), k->kbf,
// v->vpp fp32 + vtb bf16 transposed [c][n].
// ---------------------------------------------------------------------------
__global__ __launch_bounds__(256) void proj_k(
    const unsigned short* __restrict__ imgT, const unsigned short* __restrict__ wt,
    const float* __restrict__ bq, const float* __restrict__ bk, const float* __restrict__ bv,
    unsigned short* __restrict__ qbf, unsigned short* __restrict__ kbf,
    float* __restrict__ vpp, unsigned short* __restrict__ vtb)
{
  __shared__ __align__(16) unsigned short As[128][72];
  __shared__ __align__(16) unsigned short Bs[128][72];
  const int tid = threadIdx.x;
  const int w = tid >> 6, lane = tid & 63;
  const int lr = lane & 15, quad = lane >> 4;
  const int m0 = blockIdx.x * 128, n0 = blockIdx.y * 128;
  const int z = blockIdx.z, zz = z >> 1, bb = z & 1;
  const int wm = (w >> 1) * 64, wn = (w & 1) * 64;
  const int sr = tid >> 1, sh = (tid & 1) * 32;
  const long long NvCv = (long long)Nv * Cv;

  const float* bias = zz == 0 ? bq : (zz == 1 ? bk : bv);
  const unsigned short* Ab0 = imgT + (long long)z * NvCv + (long long)(m0 + sr) * Cv + sh;
  const unsigned short* Bb0 = wt + (long long)zz * 65536 + (long long)(n0 + sr) * Cv + sh;

  f32x4 acc[4][4];
#pragma unroll
  for (int i = 0; i < 4; ++i)
#pragma unroll
    for (int j = 0; j < 4; ++j) acc[i][j] = (f32x4){0.f, 0.f, 0.f, 0.f};

  for (int k0 = 0; k0 < Cv; k0 += 64) {
    const unsigned short* Ab = Ab0 + k0;
    const unsigned short* Bp = Bb0 + k0;
    uint4 a0 = *(const uint4*)Ab, a1 = *(const uint4*)(Ab + 8);
    uint4 a2 = *(const uint4*)(Ab + 16), a3 = *(const uint4*)(Ab + 24);
    uint4 b0 = *(const uint4*)Bp, b1 = *(const uint4*)(Bp + 8);
    uint4 b2 = *(const uint4*)(Bp + 16), b3 = *(const uint4*)(Bp + 24);
    *(uint4*)&As[sr][sh] = a0; *(uint4*)&As[sr][sh + 8] = a1;
    *(uint4*)&As[sr][sh + 16] = a2; *(uint4*)&As[sr][sh + 24] = a3;
    *(uint4*)&Bs[sr][sh] = b0; *(uint4*)&Bs[sr][sh + 8] = b1;
    *(uint4*)&Bs[sr][sh + 16] = b2; *(uint4*)&Bs[sr][sh + 24] = b3;
    __syncthreads();
#pragma unroll
    for (int ks = 0; ks < 2; ++ks) {
      bf16x8 af[4], bfr[4];
#pragma unroll
      for (int i = 0; i < 4; ++i)
        af[i] = *(const bf16x8*)&As[wm + i * 16 + lr][ks * 32 + quad * 8];
#pragma unroll
      for (int j = 0; j < 4; ++j)
        bfr[j] = *(const bf16x8*)&Bs[wn + j * 16 + lr][ks * 32 + quad * 8];
#pragma unroll
      for (int i = 0; i < 4; ++i)
#pragma unroll
        for (int j = 0; j < 4; ++j)
          acc[i][j] = __builtin_amdgcn_mfma_f32_16x16x32_bf16(af[i], bfr[j], acc[i][j], 0, 0, 0);
    }
    __syncthreads();
  }

#pragma unroll
  for (int j = 0; j < 4; ++j) {
    const int col = n0 + wn + j * 16 + lr;
    const float bvv = bias[col];
#pragma unroll
    for (int i = 0; i < 4; ++i) {
      const int mb = m0 + wm + i * 16 + quad * 4;
      float r[4];
#pragma unroll
      for (int reg = 0; reg < 4; ++reg) r[reg] = acc[i][j][reg] + bvv;
      const long long ob = (long long)bb * NvCv;
      if (zz == 0) {
#pragma unroll
        for (int reg = 0; reg < 4; ++reg)
          qbf[ob + (long long)(mb + reg) * Cv + col] = f2bf(r[reg] * 0.125f);
      } else if (zz == 1) {
#pragma unroll
        for (int reg = 0; reg < 4; ++reg)
          kbf[ob + (long long)(mb + reg) * Cv + col] = f2bf(r[reg]);
      } else {
#pragma unroll
        for (int reg = 0; reg < 4; ++reg)
          vpp[ob + (long long)(mb + reg) * Cv + col] = r[reg];
        uint2 pk;
        pk.x = f2bf(r[0]) | ((unsigned int)f2bf(r[1]) << 16);
        pk.y = f2bf(r[2]) | ((unsigned int)f2bf(r[3]) << 16);
        *(uint2*)&vtb[ob + (long long)col * Nv + mb] = pk;
      }
    }
  }
}

// ---------------------------------------------------------------------------
// bf16 MFMA GEMM for the MLPs (as R5). OM: 0 fp32 [m][n]; 1 bf16 [m][n];
// 4 fp32 transposed to [B][C][N] from flattened m (final output).
// ---------------------------------------------------------------------------
template<bool ABF16, int ACT, int RES, int OM>
__global__ __launch_bounds__(256) void mm_k(
    const void* __restrict__ A, const unsigned short* __restrict__ Bt,
    const float* __restrict__ bias, const float* __restrict__ Res,
    float* __restrict__ outF, unsigned short* __restrict__ outB,
    int M, int Nn, int Kd)
{
  __shared__ __align__(16) unsigned short As[128][72];
  __shared__ __align__(16) unsigned short Bs[128][72];
  const int tid = threadIdx.x;
  const int w = tid >> 6, lane = tid & 63;
  const int lr = lane & 15, quad = lane >> 4;
  const int m0 = blockIdx.x * 128, n0 = blockIdx.y * 128;
  const int wm = (w >> 1) * 64, wn = (w & 1) * 64;
  const int sr = tid >> 1, sh = (tid & 1) * 32;

  f32x4 acc[4][4];
#pragma unroll
  for (int i = 0; i < 4; ++i)
#pragma unroll
    for (int j = 0; j < 4; ++j) acc[i][j] = (f32x4){0.f, 0.f, 0.f, 0.f};

  const long long abase = (long long)(m0 + sr) * Kd + sh;
  const unsigned short* Bb = Bt + (long long)(n0 + sr) * Kd + sh;

  for (int k0 = 0; k0 < Kd; k0 += 64) {
    if (ABF16) {
      const unsigned short* Ab = (const unsigned short*)A + abase + k0;
      uint4 u0 = *(const uint4*)Ab, u1 = *(const uint4*)(Ab + 8);
      uint4 u2 = *(const uint4*)(Ab + 16), u3 = *(const uint4*)(Ab + 24);
      *(uint4*)&As[sr][sh] = u0; *(uint4*)&As[sr][sh + 8] = u1;
      *(uint4*)&As[sr][sh + 16] = u2; *(uint4*)&As[sr][sh + 24] = u3;
    } else {
      const float* Af = (const float*)A + abase + k0;
#pragma unroll
      for (int t = 0; t < 4; ++t) {
        const float4 f0 = *(const float4*)(Af + t * 8);
        const float4 f1 = *(const float4*)(Af + t * 8 + 4);
        uint4 pk;
        pk.x = f2bf(f0.x) | ((unsigned int)f2bf(f0.y) << 16);
        pk.y = f2bf(f0.z) | ((unsigned int)f2bf(f0.w) << 16);
        pk.z = f2bf(f1.x) | ((unsigned int)f2bf(f1.y) << 16);
        pk.w = f2bf(f1.z) | ((unsigned int)f2bf(f1.w) << 16);
        *(uint4*)&As[sr][sh + t * 8] = pk;
      }
    }
    {
      const unsigned short* Bp = Bb + k0;
      uint4 u0 = *(const uint4*)Bp, u1 = *(const uint4*)(Bp + 8);
      uint4 u2 = *(const uint4*)(Bp + 16), u3 = *(const uint4*)(Bp + 24);
      *(uint4*)&Bs[sr][sh] = u0; *(uint4*)&Bs[sr][sh + 8] = u1;
      *(uint4*)&Bs[sr][sh + 16] = u2; *(uint4*)&Bs[sr][sh + 24] = u3;
    }
    __syncthreads();
#pragma unroll
    for (int ks = 0; ks < 2; ++ks) {
      bf16x8 af[4], bfr[4];
#pragma unroll
      for (int i = 0; i < 4; ++i)
        af[i] = *(const bf16x8*)&As[wm + i * 16 + lr][ks * 32 + quad * 8];
#pragma unroll
      for (int j = 0; j < 4; ++j)
        bfr[j] = *(const bf16x8*)&Bs[wn + j * 16 + lr][ks * 32 + quad * 8];
#pragma unroll
      for (int i = 0; i < 4; ++i)
#pragma unroll
        for (int j = 0; j < 4; ++j)
          acc[i][j] = __builtin_amdgcn_mfma_f32_16x16x32_bf16(af[i], bfr[j], acc[i][j], 0, 0, 0);
    }
    __syncthreads();
  }

#pragma unroll
  for (int j = 0; j < 4; ++j) {
    const int col = n0 + wn + j * 16 + lr;
    const float bv = bias[col];
#pragma unroll
    for (int i = 0; i < 4; ++i) {
      const int mb = m0 + wm + i * 16 + quad * 4;
      float r[4];
#pragma unroll
      for (int reg = 0; reg < 4; ++reg) {
        float v = acc[i][j][reg] + bv;
        if (ACT) v = v > 0.f ? v : 0.01f * v;
        if (RES) v += Res[(long long)(mb + reg) * Nn + col];
        r[reg] = v;
      }
      if (OM == 0) {
#pragma unroll
        for (int reg = 0; reg < 4; ++reg)
          outF[(long long)(mb + reg) * Nn + col] = r[reg];
      } else if (OM == 1) {
#pragma unroll
        for (int reg = 0; reg < 4; ++reg)
          outB[(long long)(mb + reg) * Nn + col] = f2bf(r[reg]);
      } else {  // OM == 4: fp32 [B][C][N], m flattened over (b,n); 64B/col coalesced
        const float4 st = {r[0], r[1], r[2], r[3]};
        *(float4*)&outF[((long long)((mb >> 12) * Cv + col)) * Nv + (mb & 4095)] = st;
      }
    }
  }
}

// ---------------------------------------------------------------------------
// Cluster centers (labels prefetched to LDS -> no global-latency chain)
// ---------------------------------------------------------------------------
__global__ __launch_bounds__(256) void zero_k(float* p, int n)
{
  const int i = blockIdx.x * 256 + threadIdx.x;
  if (i < n) p[i] = 0.f;
}

__global__ __launch_bounds__(256) void center_accum(
    const unsigned short* __restrict__ kb, const int* __restrict__ labels,
    float* __restrict__ cent, float* __restrict__ cnts)
{
  __shared__ int lab_s[512];
  const int bx = blockIdx.x;           // Bv*Kv*8 blocks
  const int chunk = bx & 7;
  const int kk = (bx >> 3) & 15;
  const int b = bx >> 7;
  const int c = threadIdx.x;
  const int nbase = chunk * 512;
  for (int i = threadIdx.x; i < 512; i += 256) lab_s[i] = labels[b * Nv + nbase + i];
  __syncthreads();
  float acc = 0.f;
  int cnt = 0;
#pragma unroll 4
  for (int i = 0; i < 512; ++i) {
    if (lab_s[i] == kk) {              // wave-uniform branch on LDS value
      acc += bf2f(kb[(long long)(b * Nv + nbase + i) * Cv + c]);
      ++cnt;
    }
  }
  atomicAdd(&cent[(b * Kv + kk) * Cv + c], acc);
  if (c == 0) atomicAdd(&cnts[b * Kv + kk], (float)cnt);
}

__global__ __launch_bounds__(256) void center_norm(float* cent, const float* cnts)
{
  const int i = blockIdx.x * 256 + threadIdx.x;  // Bv*Kv*Cv
  cent[i] = cent[i] / (cnts[i >> 8] + 1e-6f);
}

// ---------------------------------------------------------------------------
// MFMA flash attention, split-m x2, fixed-max softmax (m=4), k/v/pc register
// prefetch pipeline. Block = (part, b, h, qtile). 40,704B LDS -> 4 blocks/CU.
// Partials: opart[part][b][n][c] fp32 (un-normalized), lpart[part][b][h][n].
// ---------------------------------------------------------------------------
union PSCS {
  unsigned short p[4][16][68];   // P tiles (per wave), used in main loop
  float c[16][68];               // centers, used only in prologue
};

__global__ __launch_bounds__(256) void attn_k(
    const unsigned short* __restrict__ qb, const unsigned short* __restrict__ kb,
    const unsigned short* __restrict__ vtb, const float* __restrict__ cent,
    const int* __restrict__ labels, const float* __restrict__ pc,
    float* __restrict__ opart, float* __restrict__ lpart)
{
  __shared__ __align__(16) unsigned short q_s[64][72];
  __shared__ __align__(16) unsigned short k_s[64][72];
  __shared__ __align__(16) unsigned short vt_s[64][72];
  __shared__ __align__(16) PSCS u_s;
  __shared__ float ac_s[64][17];

  const int tid = threadIdx.x;
  const int lane = tid & 63, w = tid >> 6;
  const int lr = lane & 15, quad = lane >> 4;
  const int bx = blockIdx.x;
  const int qt = bx & 63, h = (bx >> 6) & 3, b = (bx >> 8) & 1;
  const int part = bx >> 9;
  const int n0 = qt * 64;
  const int mbase = part * 2048;
  const int sr2 = tid >> 2, so2 = (tid & 3) * 16;
  const int row_l = w * 16 + quad * 4;
  const long long pcb = (long long)b * Nv * Nv;

  // ---- prologue: stage q + centers
  {
    const unsigned short* src = qb + ((long long)(b * Nv + n0 + sr2)) * Cv + h * HDv + so2;
    *(uint4*)&q_s[sr2][so2] = *(const uint4*)src;
    *(uint4*)&q_s[sr2][so2 + 8] = *(const uint4*)(src + 8);
  }
  for (int idx = tid; idx < Kv * HDv; idx += 256)
    u_s.c[idx >> 6][idx & 63] = cent[((long long)(b * Kv + (idx >> 6))) * Cv + h * HDv + (idx & 63)];

  // issue tile-0 k/v + pc + labm loads while the block syncs
  uint4 ka0, ka1, va0, va1;
  float pc1[4][4];
  int labm1[4], labq[4];
  {
    const long long ks = ((long long)(b * Nv + mbase + sr2)) * Cv + h * HDv + so2;
    ka0 = *(const uint4*)(kb + ks); ka1 = *(const uint4*)(kb + ks + 8);
    const long long vs = ((long long)(b * Cv + h * HDv + sr2)) * Nv + mbase + so2;
    va0 = *(const uint4*)(vtb + vs); va1 = *(const uint4*)(vtb + vs + 8);
  }
#pragma unroll
  for (int sub = 0; sub < 4; ++sub) {
    labm1[sub] = labels[b * Nv + mbase + sub * 16 + lr];
#pragma unroll
    for (int reg = 0; reg < 4; ++reg)
      pc1[sub][reg] = pc[pcb + (long long)(n0 + row_l + reg) * Nv + mbase + sub * 16 + lr];
  }
#pragma unroll
  for (int reg = 0; reg < 4; ++reg) labq[reg] = labels[b * Nv + n0 + row_l + reg];

  __syncthreads();               // q_s, u_s.c visible
  // ac_s[r][k] = (q_r/8) . center_k
  for (int idx = tid; idx < 64 * Kv; idx += 256) {
    const int r = idx >> 4, kk = idx & 15;
    float s = 0.f;
#pragma unroll
    for (int d = 0; d < HDv; ++d) s += bf2f(q_s[r][d]) * u_s.c[kk][d];
    ac_s[r][kk] = s;
  }
  const bf16x8 qa0 = *(const bf16x8*)&q_s[w * 16 + lr][quad * 8];
  const bf16x8 qa1 = *(const bf16x8*)&q_s[w * 16 + lr][32 + quad * 8];
  __syncthreads();               // ac_s visible; all waves done with u_s.c

  // stage tile 0 from regs
  *(uint4*)&k_s[sr2][so2] = ka0; *(uint4*)&k_s[sr2][so2 + 8] = ka1;
  *(uint4*)&vt_s[sr2][so2] = va0; *(uint4*)&vt_s[sr2][so2 + 8] = va1;
  __syncthreads();               // tile 0 visible

  f32x4 oacc[4];
#pragma unroll
  for (int s2 = 0; s2 < 4; ++s2) oacc[s2] = (f32x4){0.f, 0.f, 0.f, 0.f};
  float lrow[4] = {0.f, 0.f, 0.f, 0.f};

  for (int t = 0; t < 32; ++t) {
    const int m0 = mbase + t * 64;
    const bool has = (t < 31);

    // prefetch next tile k/v into regs (hidden behind this tile's compute)
    if (has) {
      const long long ks = ((long long)(b * Nv + m0 + 64 + sr2)) * Cv + h * HDv + so2;
      ka0 = *(const uint4*)(kb + ks); ka1 = *(const uint4*)(kb + ks + 8);
      const long long vs = ((long long)(b * Cv + h * HDv + sr2)) * Nv + m0 + 64 + so2;
      va0 = *(const uint4*)(vtb + vs); va1 = *(const uint4*)(vtb + vs + 8);
    }

    // QK^T
    f32x4 sacc[4];
#pragma unroll
    for (int sub = 0; sub < 4; ++sub) {
      const bf16x8 kb0 = *(const bf16x8*)&k_s[sub * 16 + lr][quad * 8];
      const bf16x8 kb1 = *(const bf16x8*)&k_s[sub * 16 + lr][32 + quad * 8];
      f32x4 s = (f32x4){0.f, 0.f, 0.f, 0.f};
      s = __builtin_amdgcn_mfma_f32_16x16x32_bf16(qa0, kb0, s, 0, 0, 0);
      s = __builtin_amdgcn_mfma_f32_16x16x32_bf16(qa1, kb1, s, 0, 0, 0);
      sacc[sub] = s;
    }

    // adaptive select + exp(s-4), accumulate denominator
#pragma unroll
    for (int reg = 0; reg < 4; ++reg) {
      const int Ln = labq[reg];
#pragma unroll
      for (int sub = 0; sub < 4; ++sub) {
        const float s = (labm1[sub] == Ln) ? sacc[sub][reg]
                                           : ac_s[row_l + reg][labm1[sub]] * pc1[sub][reg];
        const float p = __expf(s - 4.0f);
        lrow[reg] += p;
        u_s.p[w][quad * 4 + reg][sub * 16 + lr] = f2bf(p);
      }
    }

    // pc/labm consumed -> issue next tile's (covers PV + barriers + next QK)
    if (has) {
#pragma unroll
      for (int sub = 0; sub < 4; ++sub) {
        labm1[sub] = labels[b * Nv + m0 + 64 + sub * 16 + lr];
#pragma unroll
        for (int reg = 0; reg < 4; ++reg)
          pc1[sub][reg] = pc[pcb + (long long)(n0 + row_l + reg) * Nv + m0 + 64 + sub * 16 + lr];
      }
    }

    // PV (same-wave LDS in-order)
    const bf16x8 pa0 = *(const bf16x8*)&u_s.p[w][lr][quad * 8];
    const bf16x8 pa1 = *(const bf16x8*)&u_s.p[w][lr][32 + quad * 8];
#pragma unroll
    for (int sub = 0; sub < 4; ++sub) {
      const bf16x8 vb0 = *(const bf16x8*)&vt_s[sub * 16 + lr][quad * 8];
      const bf16x8 vb1 = *(const bf16x8*)&vt_s[sub * 16 + lr][32 + quad * 8];
      oacc[sub] = __builtin_amdgcn_mfma_f32_16x16x32_bf16(pa0, vb0, oacc[sub], 0, 0, 0);
      oacc[sub] = __builtin_amdgcn_mfma_f32_16x16x32_bf16(pa1, vb1, oacc[sub], 0, 0, 0);
    }

    __syncthreads();             // all waves done reading k_s/vt_s
    if (has) {
      *(uint4*)&k_s[sr2][so2] = ka0; *(uint4*)&k_s[sr2][so2 + 8] = ka1;
      *(uint4*)&vt_s[sr2][so2] = va0; *(uint4*)&vt_s[sr2][so2 + 8] = va1;
    }
    __syncthreads();             // next tile visible
  }

  // epilogue: partial sums (no normalization; combine_k divides)
#pragma unroll
  for (int reg = 0; reg < 4; ++reg) {
    float l = lrow[reg];
    l += __shfl_xor(l, 1); l += __shfl_xor(l, 2);
    l += __shfl_xor(l, 4); l += __shfl_xor(l, 8);
    const int row = n0 + row_l + reg;
    const long long obase = (long long)part * 2097152 + ((long long)(b * Nv + row)) * Cv + h * HDv;
#pragma unroll
    for (int sub = 0; sub < 4; ++sub)
      opart[obase + sub * 16 + lr] = oacc[sub][reg];
    if (lr == 0)
      lpart[part * 32768 + (b * 4 + h) * 4096 + row] = l;
  }
}

// ---------------------------------------------------------------------------
// Combine split-m partials: aob = (o0+o1)/(l0+l1), bf16
// ---------------------------------------------------------------------------
__global__ __launch_bounds__(256) void combine_k(
    const float* __restrict__ op, const float* __restrict__ lp,
    unsigned short* __restrict__ aob)
{
  const long long i4 = ((long long)blockIdx.x * 256 + threadIdx.x) * 4;
  const int c = (int)(i4 & 255), n = (int)((i4 >> 8) & 4095), b = (int)(i4 >> 20);
  const int h = c >> 6;
  const float l = lp[(b * 4 + h) * 4096 + n] + lp[32768 + (b * 4 + h) * 4096 + n];
  const float inv = 1.f / l;
  const float4 a = *(const float4*)&op[i4];
  const float4 d = *(const float4*)&op[2097152 + i4];
  uint2 pk;
  pk.x = f2bf((a.x + d.x) * inv) | ((unsigned int)f2bf((a.y + d.y) * inv) << 16);
  pk.y = f2bf((a.z + d.z) * inv) | ((unsigned int)f2bf((a.w + d.w) * inv) << 16);
  *(uint2*)&aob[i4] = pk;
}

// ---------------------------------------------------------------------------
extern "C" void kernel_launch(void* const* d_in, const int* in_sizes, int n_in,
                              void* d_out, int out_size, void* d_ws, size_t ws_size,
                              hipStream_t stream)
{
  const float* q_img = (const float*)d_in[0];
  const float* k_img = (const float*)d_in[1];
  const float* v_img = (const float*)d_in[2];
  const int* labels  = (const int*)d_in[3];
  const float* pc    = (const float*)d_in[4];
  const float* Wq  = (const float*)d_in[5];  const float* bq  = (const float*)d_in[6];
  const float* Wk  = (const float*)d_in[7];  const float* bk  = (const float*)d_in[8];
  const float* Wv  = (const float*)d_in[9];  const float* bv  = (const float*)d_in[10];
  const float* W11 = (const float*)d_in[11]; const float* b11 = (const float*)d_in[12];
  const float* W12 = (const float*)d_in[13]; const float* b12 = (const float*)d_in[14];
  const float* W21 = (const float*)d_in[15]; const float* b21 = (const float*)d_in[16];
  const float* W22 = (const float*)d_in[17]; const float* b22 = (const float*)d_in[18];
  float* outp = (float*)d_out;

  const long long SZ = (long long)Bv * Nv * Cv;     // 2,097,152
  // fp32 region (~32.3 MB)
  float* ws    = (float*)d_ws;
  float* vpp   = ws;                       // v proj fp32
  float* rs1   = vpp + SZ;                 // MLP1 out fp32
  float* opart = rs1 + SZ;                 // attn partials [2][B][N][C]
  float* lpart = opart + 2 * SZ;           // [2][B][NH][N]
  float* cent  = lpart + 65536;            // [B][K][C]
  float* cnts  = cent + Bv * Kv * Cv;      // [B][K]
  // bf16 region (~25.4 MB)
  unsigned short* wt   = (unsigned short*)(cnts + Bv * Kv);
  unsigned short* qbf  = wt + 720896;      // [B][N][C] pre-scaled 1/8
  unsigned short* kbf  = qbf + SZ;
  unsigned short* vtb  = kbf + SZ;         // [B][C][N]
  unsigned short* aob  = vtb + SZ;         // attn out bf16
  unsigned short* h1b  = aob + SZ;         // MLP hidden [2N][2C]
  unsigned short* imgT = aob;              // overlay (dead after proj_k)

  // prep
  imgt_k<<<dim3(Nv / 32, Cv / 32, 6), dim3(32, 8), 0, stream>>>(q_img, k_img, v_img, imgT);
  WP wp = {{Wq, Wk, Wv, W11, W12, W21, W22}};
  wt_k<<<dim3(16, 16, 7), dim3(32, 8), 0, stream>>>(wp, wt);

  // fused q/k/v projections (one dispatch, 384 blocks)
  proj_k<<<dim3(32, 2, 6), 256, 0, stream>>>(imgT, wt, bq, bk, bv, qbf, kbf, vpp, vtb);

  // cluster centers
  zero_k<<<dim3(33), 256, 0, stream>>>(cent, Bv * Kv * Cv + Bv * Kv);
  center_accum<<<dim3(Bv * Kv * 8), 256, 0, stream>>>(kbf, labels, cent, cnts);
  center_norm<<<dim3(Bv * Kv * Cv / 256), 256, 0, stream>>>(cent, cnts);

  // attention (split-m x2) + combine
  attn_k<<<dim3(1024), 256, 0, stream>>>(qbf, kbf, vtb, cent, labels, pc, opart, lpart);
  combine_k<<<dim3(2048), 256, 0, stream>>>(opart, lpart, aob);

  // MLP1: h1 = leaky(aob@W11+b11); rs1 = vpp + h1@W12+b12
  mm_k<true, 1, 0, 1><<<dim3(64, 4), 256, 0, stream>>>(
      aob, wt + 196608, b11, nullptr, nullptr, h1b, 2 * Nv, 2 * Cv, Cv);
  mm_k<true, 0, 1, 0><<<dim3(64, 2), 256, 0, stream>>>(
      h1b, wt + 327680, b12, vpp, rs1, nullptr, 2 * Nv, Cv, 2 * Cv);

  // MLP2: h2 = leaky(rs1@W21+b21); out = rs1 + h2@W22+b22 -> [B][C][H][W]
  mm_k<false, 1, 0, 1><<<dim3(64, 4), 256, 0, stream>>>(
      rs1, wt + 458752, b21, nullptr, nullptr, h1b, 2 * Nv, 2 * Cv, Cv);
  mm_k<true, 0, 1, 4><<<dim3(64, 2), 256, 0, stream>>>(
      h1b, wt + 589824, b22, rs1, outp, nullptr, 2 * Nv, Cv, 2 * Cv);
}